// Round 2
// baseline (267.622 us; speedup 1.0000x reference)
//
#include <hip/hip_runtime.h>

#define H 512
#define W 512
#define HW (H * W)
#define T 128
#define DECAY 0.8f

#define TS 32           // output tile (square)
#define RG 40           // region = TS + 2*4 halo
#define RS 44           // LDS row stride (words) -> uniform bank spread for b128
#define NELEM (RG * RG) // 1600 region elements
#define KPT 7           // ceil(1600/256) update elements per thread

// One block = one 32x32 spatial tile for ALL 128 timesteps.
//   p (cell-1 current): thread-private registers, pointwise update.
//   r (cell-2 conv input): LDS, double-buffered (read r_cur, write r_nxt)
//   -> single __syncthreads per timestep.
// out[t] = conv9x9(r entering step t); r' = 0.8 r + p_old; p' = 0.8 p + x[t].
__global__ __launch_bounds__(256, 1) void snn_fused(
    const float* __restrict__ x, const float* __restrict__ w,
    float* __restrict__ out)
{
    __shared__ float rA[RG * RS];
    __shared__ float rB[RG * RS];
    __shared__ float wsm[81];

    const int tid = threadIdx.x;
    const int tileX = blockIdx.x, tileY = blockIdx.y;
    const int X0 = tileX * TS - 4, Y0 = tileY * TS - 4;

    if (tid < 81) wsm[tid] = w[tid];
    for (int e = tid; e < RG * RS; e += 256) { rA[e] = 0.f; rB[e] = 0.f; }

    // ---- per-thread update-element setup (static for whole kernel) ----
    int goff[KPT], laddr[KPT];
    unsigned vmask = 0, emask = 0;
    #pragma unroll
    for (int k = 0; k < KPT; ++k) {
        int e = tid + k * 256;
        int ly = e / RG, lx = e - ly * RG;
        int gy = Y0 + ly, gx = X0 + lx;
        bool inimg = ((unsigned)gy < H) && ((unsigned)gx < W);
        bool inreg = (e < NELEM);
        goff[k] = inimg ? (gy * W + gx) : 0;
        laddr[k] = ly * RS + lx;
        if (inimg && inreg) vmask |= (1u << k);
        if (inreg) emask |= (1u << k);
    }

    // ---- conv run setup: thread -> 4-wide run ----
    const int rx = tid & 7;   // 8 runs per row (32/4)
    const int ry = tid >> 3;  // 0..31 output row
    const int cbase = ry * RS + rx * 4;
    float* outp = out + (size_t)(tileY * TS + ry) * W + tileX * TS + rx * 4;

    __syncthreads();

    // weights -> VGPRs once (grid is 1 block/CU: register pressure is free)
    float wr[81];
    #pragma unroll
    for (int i = 0; i < 81; ++i) wr[i] = wsm[i];

    float p[KPT];
    #pragma unroll
    for (int k = 0; k < KPT; ++k) p[k] = 0.f;

    // prologue: x[0]
    float xv[KPT];
    #pragma unroll
    for (int k = 0; k < KPT; ++k)
        xv[k] = (vmask >> k & 1) ? x[goff[k]] : 0.f;

#define STEP(tcur, RC, RN)                                                   \
    {                                                                        \
        /* prefetch x[t+1] (consumed next iteration) */                      \
        int tnx = ((tcur) + 1 < T) ? ((tcur) + 1) : (T - 1);                 \
        const float* xnp = x + (size_t)tnx * HW;                             \
        float xn[KPT];                                                       \
        _Pragma("unroll")                                                    \
        for (int k = 0; k < KPT; ++k)                                        \
            xn[k] = (vmask >> k & 1) ? xnp[goff[k]] : 0.f;                   \
        /* conv from RC */                                                   \
        float acc0 = 0.f, acc1 = 0.f, acc2 = 0.f, acc3 = 0.f;                \
        _Pragma("unroll")                                                    \
        for (int ky = 0; ky < 9; ++ky) {                                     \
            const float* rp = RC + cbase + ky * RS;                          \
            float4 w0 = *(const float4*)(rp);                                \
            float4 w1 = *(const float4*)(rp + 4);                            \
            float4 w2 = *(const float4*)(rp + 8);                            \
            float win[12] = {w0.x, w0.y, w0.z, w0.w, w1.x, w1.y,             \
                             w1.z, w1.w, w2.x, w2.y, w2.z, w2.w};            \
            _Pragma("unroll")                                                \
            for (int kx = 0; kx < 9; ++kx) {                                 \
                float wv = wr[ky * 9 + kx];                                  \
                acc0 = __builtin_fmaf(wv, win[kx + 0], acc0);                \
                acc1 = __builtin_fmaf(wv, win[kx + 1], acc1);                \
                acc2 = __builtin_fmaf(wv, win[kx + 2], acc2);                \
                acc3 = __builtin_fmaf(wv, win[kx + 3], acc3);                \
            }                                                                \
        }                                                                    \
        *(float4*)(outp + (size_t)(tcur) * HW) =                             \
            make_float4(acc0, acc1, acc2, acc3);                             \
        /* state update: r_nxt = 0.8 r_cur + p_old ; p = 0.8 p + x[t] */     \
        _Pragma("unroll")                                                    \
        for (int k = 0; k < KPT; ++k) {                                      \
            if (emask >> k & 1) {                                            \
                float rcv = RC[laddr[k]];                                    \
                RN[laddr[k]] = __builtin_fmaf(DECAY, rcv, p[k]);             \
                p[k] = __builtin_fmaf(DECAY, p[k], xv[k]);                   \
            }                                                                \
        }                                                                    \
        _Pragma("unroll")                                                    \
        for (int k = 0; k < KPT; ++k) xv[k] = xn[k];                         \
        __syncthreads();                                                     \
    }

    for (int t = 0; t < T; t += 2) {
        STEP(t, rA, rB);
        STEP(t + 1, rB, rA);
    }
#undef STEP
}

extern "C" void kernel_launch(void* const* d_in, const int* in_sizes, int n_in,
                              void* d_out, int out_size, void* d_ws, size_t ws_size,
                              hipStream_t stream) {
    const float* x = (const float*)d_in[0]; // [128,1,512,512]
    const float* w = (const float*)d_in[1]; // [1,1,9,9]
    float* out = (float*)d_out;             // [128,1,512,512]
    (void)d_ws; (void)ws_size;

    snn_fused<<<dim3(W / TS, H / TS), 256, 0, stream>>>(x, w, out);
}